// Round 2
// baseline (682.570 us; speedup 1.0000x reference)
//
#include <hip/hip_runtime.h>
#include <math.h>

#define N_NODES 1024
#define HDIM    128

typedef float f4 __attribute__((ext_vector_type(4)));

// One block per node i. 256 threads = 8 groups of 32 lanes; each group
// streams active edge-embedding rows (512 B, float4-coalesced), 4 rows in
// flight. Edge-table reads are nontemporal (streamed once, keep L2 for
// nf/w). Active-j list built with an ordered wave-scan compaction.
__global__ __launch_bounds__(256) void motif_gru_kernel(
    const float* __restrict__ nf,     // [N, H]
    const int*   __restrict__ adj,    // [N, N]
    const float* __restrict__ T,      // [N*N, H]
    const float* __restrict__ w_ih,   // [3H, H]
    const float* __restrict__ w_hh,   // [3H, H]
    const float* __restrict__ b_ih,   // [3H]
    const float* __restrict__ b_hh,   // [3H]
    float*       __restrict__ out)    // [N, H]
{
    const int i    = blockIdx.x;
    const int tid  = threadIdx.x;
    const int wave = tid >> 6;
    const int l64  = tid & 63;

    __shared__ int   s_list[N_NODES];   // sorted active-j list
    __shared__ int   s_wsum[4];         // per-wave active counts
    __shared__ float s_red[8][HDIM];    // per-group partial sums
    __shared__ float s_agg[HDIM];
    __shared__ float s_nfi[HDIM];
    __shared__ float s_gi[3 * HDIM];
    __shared__ float s_gh[3 * HDIM];

    // ---- Phase 1: ordered compaction. Thread tid owns j = 4*tid..4*tid+3,
    // so wave w owns j in [256w, 256w+256) -> list is globally sorted.
    const int4 a = reinterpret_cast<const int4*>(adj + (size_t)i * N_NODES)[tid];
    const int m0 = (a.x != 0), m1 = (a.y != 0), m2 = (a.z != 0), m3 = (a.w != 0);
    unsigned c = (unsigned)(m0 + m1 + m2 + m3);
    unsigned inc = c;
    #pragma unroll
    for (int d = 1; d < 64; d <<= 1) {
        unsigned v = __shfl_up(inc, d);
        if (l64 >= d) inc += v;
    }
    if (l64 == 63) s_wsum[wave] = (int)inc;
    if (tid < HDIM) s_nfi[tid] = nf[(size_t)i * HDIM + tid];
    __syncthreads();

    int wbase = 0;
    #pragma unroll
    for (int w = 0; w < 4; ++w) if (w < wave) wbase += s_wsum[w];
    int pos = wbase + (int)(inc - c);
    const int j4 = tid * 4;
    if (m0) s_list[pos++] = j4;
    if (m1) s_list[pos++] = j4 + 1;
    if (m2) s_list[pos++] = j4 + 2;
    if (m3) s_list[pos++] = j4 + 3;
    __syncthreads();
    const int cnt = s_wsum[0] + s_wsum[1] + s_wsum[2] + s_wsum[3];

    // ---- Phase 2: agg[i,h] = sum_{active j} nf[j,h] * T[i,j,h]
    const int g    = tid >> 5;   // group 0..7
    const int lane = tid & 31;   // 32 lanes x float4 = 128 floats/row

    const f4* Tv  = reinterpret_cast<const f4*>(T);
    const f4* nfv = reinterpret_cast<const f4*>(nf);
    const size_t rowbase = (size_t)i * N_NODES;

    f4 acc = {0.f, 0.f, 0.f, 0.f};

    int base = 0;
    for (; base + 32 <= cnt; base += 32) {      // 4 rows in flight per group
        const int j0 = s_list[base      + g];
        const int j1 = s_list[base +  8 + g];
        const int j2 = s_list[base + 16 + g];
        const int j3 = s_list[base + 24 + g];
        f4 t0 = __builtin_nontemporal_load(&Tv[(rowbase + (size_t)j0) * 32 + lane]);
        f4 t1 = __builtin_nontemporal_load(&Tv[(rowbase + (size_t)j1) * 32 + lane]);
        f4 t2 = __builtin_nontemporal_load(&Tv[(rowbase + (size_t)j2) * 32 + lane]);
        f4 t3 = __builtin_nontemporal_load(&Tv[(rowbase + (size_t)j3) * 32 + lane]);
        f4 n0 = nfv[(size_t)j0 * 32 + lane];
        f4 n1 = nfv[(size_t)j1 * 32 + lane];
        f4 n2 = nfv[(size_t)j2 * 32 + lane];
        f4 n3 = nfv[(size_t)j3 * 32 + lane];
        acc += t0 * n0;
        acc += t1 * n1;
        acc += t2 * n2;
        acc += t3 * n3;
    }
    for (; base + 8 <= cnt; base += 8) {
        const int j0 = s_list[base + g];
        f4 t0 = __builtin_nontemporal_load(&Tv[(rowbase + (size_t)j0) * 32 + lane]);
        f4 n0 = nfv[(size_t)j0 * 32 + lane];
        acc += t0 * n0;
    }
    if (base + g < cnt) {
        const int j0 = s_list[base + g];
        f4 t0 = __builtin_nontemporal_load(&Tv[(rowbase + (size_t)j0) * 32 + lane]);
        f4 n0 = nfv[(size_t)j0 * 32 + lane];
        acc += t0 * n0;
    }

    reinterpret_cast<f4*>(&s_red[g][0])[lane] = acc;
    __syncthreads();

    if (tid < HDIM) {
        float s = 0.f;
        #pragma unroll
        for (int gg = 0; gg < 8; ++gg) s += s_red[gg][tid];
        s_agg[tid] = s;
    }
    __syncthreads();

    // ---- Phase 3: GRU matvecs (w_* L2-hot; agg/nf LDS-broadcast)
    const f4* aggv = reinterpret_cast<const f4*>(s_agg);
    const f4* nfiv = reinterpret_cast<const f4*>(s_nfi);
    for (int ci = tid; ci < 3 * HDIM; ci += 256) {
        const f4* wi = reinterpret_cast<const f4*>(w_ih + (size_t)ci * HDIM);
        const f4* wh = reinterpret_cast<const f4*>(w_hh + (size_t)ci * HDIM);
        f4 gs4 = {0.f, 0.f, 0.f, 0.f};
        f4 hs4 = {0.f, 0.f, 0.f, 0.f};
        #pragma unroll 8
        for (int k = 0; k < HDIM / 4; ++k) {
            gs4 += wi[k] * aggv[k];
            hs4 += wh[k] * nfiv[k];
        }
        s_gi[ci] = gs4.x + gs4.y + gs4.z + gs4.w + b_ih[ci];
        s_gh[ci] = hs4.x + hs4.y + hs4.z + hs4.w + b_hh[ci];
    }
    __syncthreads();

    // ---- Phase 4: gates + output
    if (tid < HDIM) {
        float r  = 1.f / (1.f + expf(-(s_gi[tid] + s_gh[tid])));
        float z  = 1.f / (1.f + expf(-(s_gi[HDIM + tid] + s_gh[HDIM + tid])));
        float nn = tanhf(s_gi[2 * HDIM + tid] + r * s_gh[2 * HDIM + tid]);
        out[(size_t)i * HDIM + tid] = (1.f - z) * nn + z * s_nfi[tid];
    }
}

extern "C" void kernel_launch(void* const* d_in, const int* in_sizes, int n_in,
                              void* d_out, int out_size, void* d_ws, size_t ws_size,
                              hipStream_t stream) {
    const float* nf   = (const float*)d_in[0];
    const int*   adj  = (const int*)d_in[1];
    const float* T    = (const float*)d_in[2];
    const float* w_ih = (const float*)d_in[3];
    const float* w_hh = (const float*)d_in[4];
    const float* b_ih = (const float*)d_in[5];
    const float* b_hh = (const float*)d_in[6];
    float* out = (float*)d_out;

    motif_gru_kernel<<<dim3(N_NODES), dim3(256), 0, stream>>>(
        nf, adj, T, w_ih, w_hh, b_ih, b_hh, out);
}